// Round 1
// baseline (385.251 us; speedup 1.0000x reference)
//
#include <hip/hip_runtime.h>
#include <hip/hip_bf16.h>

// Flash-attention fwd, causal + key-padding mask. B=8,S=2048,D=512 fp32.
// bf16 MFMA 16x16x32, f32 online softmax. One block = 64 q-rows (4 waves x 16),
// KV tile = 32. K linear-padded in LDS, V transposed+chunk-swizzled in LDS.

typedef short bf16x8 __attribute__((ext_vector_type(8)));
typedef short s4v    __attribute__((ext_vector_type(4)));
typedef float f32x4  __attribute__((ext_vector_type(4)));
typedef float f4v    __attribute__((ext_vector_type(4)));

#define DEVINL __device__ __forceinline__

constexpr int kS = 2048;
constexpr int kD = 512;
constexpr int KROW = kD + 8;  // 520 shorts/row: 16B-aligned rows, spreads bank quads
// scale = 1/sqrt(512); fold log2(e) so p = exp2((s_raw - m_raw)*kC)
constexpr float kC = 1.4426950408889634f * 0.044194173824159216f;

DEVINL float fast_exp2(float x) {
  float r; asm("v_exp_f32 %0, %1" : "=v"(r) : "v"(x)); return r;
}
DEVINL short f2b(float f) {
  return (short)__builtin_bit_cast(unsigned short, __float2bfloat16(f));
}
DEVINL f32x4 mfma16(bf16x8 a, bf16x8 b, f32x4 c) {
  return __builtin_amdgcn_mfma_f32_16x16x32_bf16(a, b, c, 0, 0, 0);
}

__global__ __launch_bounds__(256) void attn_fwd(
    const float* __restrict__ Qp, const float* __restrict__ Kp,
    const float* __restrict__ Vp, const int* __restrict__ Mp,
    float* __restrict__ Op) {
  __shared__ __align__(16) short Klds[32 * KROW];   // 33,280 B
  __shared__ __align__(16) short Vlds[32 * kD];     // 32,768 B, transposed+swizzled
  __shared__ __align__(16) short Plds[4 * 16 * 40]; // 5,120 B (per-wave P buffers)
  __shared__ int Mlds[kS];                          // 8,192 B padding mask

  const int tid  = threadIdx.x;
  const int lane = tid & 63;
  const int w    = tid >> 6;          // wave 0..3 -> q rows [16w,16w+16)
  const int bb   = blockIdx.x & 7;    // batch; &7 groups a batch onto one XCD
  const int qt   = blockIdx.x >> 3;   // q-tile 0..31
  const int qb   = qt * 64;

  // stage padding mask once
  for (int i = tid; i < kS; i += 256) Mlds[i] = Mp[(size_t)bb * kS + i];

  const int l15 = lane & 15, lg = lane >> 4;

  // Q A-fragments resident: qa[k] covers d = k*32 + lg*8 + e, row = qb+16w+l15
  bf16x8 qa[16];
  {
    const float* qp = Qp + ((size_t)bb * kS + qb + w * 16 + l15) * kD + lg * 8;
#pragma unroll
    for (int k = 0; k < 16; ++k) {
      f4v a = *(const f4v*)(qp + k * 32);
      f4v b = *(const f4v*)(qp + k * 32 + 4);
      bf16x8 q8 = {f2b(a[0]), f2b(a[1]), f2b(a[2]), f2b(a[3]),
                   f2b(b[0]), f2b(b[1]), f2b(b[2]), f2b(b[3])};
      qa[k] = q8;
    }
  }

  f32x4 acc[32];
#pragma unroll
  for (int dc = 0; dc < 32; ++dc) acc[dc] = f32x4{0.f, 0.f, 0.f, 0.f};
  float mrow[4] = {-1e30f, -1e30f, -1e30f, -1e30f};
  float lsum[4] = {0.f, 0.f, 0.f, 0.f};

  short* Pl = &Plds[w * 16 * 40];
  const int vphys = ((lg ^ ((lane >> 2) & 3)) * 16);  // swizzled chunk byte off (read)

  const int nt = 2 * qt + 2;  // kv tiles needed for causal rows [qb, qb+63]
  for (int t = 0; t < nt; ++t) {
    const int kv0 = t * 32;
    __syncthreads();  // previous tile's compute done; LDS reusable

    // ---- stage K tile: linear rows, 8 threads/row, coalesced f32x4 loads ----
    {
      const int r = tid >> 3, dg = tid & 7;
      const float* src = Kp + ((size_t)bb * kS + kv0 + r) * kD + dg * 64;
      short* dst = &Klds[r * KROW + dg * 64];
#pragma unroll
      for (int i = 0; i < 16; ++i) {
        f4v v = *(const f4v*)(src + i * 4);
        s4v s = {f2b(v[0]), f2b(v[1]), f2b(v[2]), f2b(v[3])};
        *(s4v*)(dst + i * 4) = s;
      }
    }
    // ---- stage V tile: 4x4 register transpose -> Vt[d][kv], chunk-swizzled ----
    {
      const int kvq = tid & 7, dqi = tid >> 3;
      const float* vbase = Vp + ((size_t)bb * kS + kv0 + kvq * 4) * kD;
#pragma unroll
      for (int it = 0; it < 4; ++it) {
        const int dq = dqi + 32 * it;   // d-quad 0..127
        f4v v0 = *(const f4v*)(vbase + 0 * kD + dq * 4);
        f4v v1 = *(const f4v*)(vbase + 1 * kD + dq * 4);
        f4v v2 = *(const f4v*)(vbase + 2 * kD + dq * 4);
        f4v v3 = *(const f4v*)(vbase + 3 * kD + dq * 4);
        const int pch = (((kvq >> 1) ^ (dq & 3)) * 16) + (kvq & 1) * 8;
#pragma unroll
        for (int c = 0; c < 4; ++c) {
          s4v s = {f2b(v0[c]), f2b(v1[c]), f2b(v2[c]), f2b(v3[c])};
          *(s4v*)((char*)Vlds + (dq * 4 + c) * 64 + pch) = s;
        }
      }
    }
    __syncthreads();

    // ---- QK^T: S[16q x 32kv], 4 independent MFMA chains ----
    f32x4 sA = {0.f,0.f,0.f,0.f}, sB = {0.f,0.f,0.f,0.f};
    f32x4 sC = {0.f,0.f,0.f,0.f}, sD = {0.f,0.f,0.f,0.f};
    const short* krow0 = &Klds[l15 * KROW + lg * 8];
    const short* krow1 = krow0 + 16 * KROW;
#pragma unroll
    for (int k = 0; k < 16; k += 2) {
      bf16x8 b00 = *(const bf16x8*)(krow0 + k * 32);
      bf16x8 b10 = *(const bf16x8*)(krow1 + k * 32);
      bf16x8 b01 = *(const bf16x8*)(krow0 + (k + 1) * 32);
      bf16x8 b11 = *(const bf16x8*)(krow1 + (k + 1) * 32);
      sA = mfma16(qa[k], b00, sA);
      sB = mfma16(qa[k], b10, sB);
      sC = mfma16(qa[k + 1], b01, sC);
      sD = mfma16(qa[k + 1], b11, sD);
    }
    f32x4 s0 = sA + sC;  // kv cols kv0+l15       (rows lg*4+j)
    f32x4 s1 = sB + sD;  // kv cols kv0+16+l15

    // ---- mask + row max (reduce over lane bits 0..3 = 16 kv cols) ----
    const int kvg0 = kv0 + l15, kvg1 = kvg0 + 16;
    const int mk0 = Mlds[kvg0], mk1 = Mlds[kvg1];
    const int qrow0 = qb + w * 16 + lg * 4;
    float rm[4];
#pragma unroll
    for (int j = 0; j < 4; ++j) {
      const int q = qrow0 + j;
      float x0 = (kvg0 <= q && mk0 != 0) ? s0[j] : -1e30f;
      float x1 = (kvg1 <= q && mk1 != 0) ? s1[j] : -1e30f;
      s0[j] = x0; s1[j] = x1;
      rm[j] = fmaxf(x0, x1);
    }
#pragma unroll
    for (int sh = 1; sh <= 8; sh <<= 1) {
#pragma unroll
      for (int j = 0; j < 4; ++j) rm[j] = fmaxf(rm[j], __shfl_xor(rm[j], sh));
    }

    // ---- defer-max rescale (T13): only when max grows > 8 in log2 domain ----
    bool need = false;
#pragma unroll
    for (int j = 0; j < 4; ++j) need |= ((rm[j] - mrow[j]) * kC > 8.0f);
    if (__any(need)) {
#pragma unroll
      for (int j = 0; j < 4; ++j) {
        float mn = fmaxf(mrow[j], rm[j]);
        float corr = fast_exp2((mrow[j] - mn) * kC);
        mrow[j] = mn;
        lsum[j] *= corr;
#pragma unroll
        for (int dc = 0; dc < 32; ++dc) acc[dc][j] *= corr;
      }
    }

    // ---- P = exp2((s-m)*kC); row-sum; write P to wave-local LDS (C->A layout) ----
    float ts[4];
#pragma unroll
    for (int j = 0; j < 4; ++j) {
      float p0 = fast_exp2((s0[j] - mrow[j]) * kC);
      float p1 = fast_exp2((s1[j] - mrow[j]) * kC);
      ts[j] = p0 + p1;
      Pl[(lg * 4 + j) * 40 + l15]      = f2b(p0);
      Pl[(lg * 4 + j) * 40 + 16 + l15] = f2b(p1);
    }
#pragma unroll
    for (int sh = 1; sh <= 8; sh <<= 1) {
#pragma unroll
      for (int j = 0; j < 4; ++j) ts[j] += __shfl_xor(ts[j], sh);
    }
#pragma unroll
    for (int j = 0; j < 4; ++j) lsum[j] += ts[j];

    // ---- PV: O[16q x 512] += P[16x32] * V[32x512] ----
    bf16x8 pf = *(const bf16x8*)&Pl[l15 * 40 + lg * 8];  // A-frag, reused 32x
#pragma unroll
    for (int dc = 0; dc < 32; ++dc) {
      const bf16x8 vf =
          *(const bf16x8*)((const char*)Vlds + (dc * 16 + l15) * 64 + vphys);
      acc[dc] = mfma16(pf, vf, acc[dc]);
    }
  }

  // ---- epilogue: O / l ----
#pragma unroll
  for (int j = 0; j < 4; ++j) {
    const float inv = __builtin_amdgcn_rcpf(lsum[j]);
    float* op = Op + ((size_t)bb * kS + qb + w * 16 + lg * 4 + j) * kD + l15;
#pragma unroll
    for (int dc = 0; dc < 32; ++dc) op[dc * 16] = acc[dc][j] * inv;
  }
}

extern "C" void kernel_launch(void* const* d_in, const int* in_sizes, int n_in,
                              void* d_out, int out_size, void* d_ws, size_t ws_size,
                              hipStream_t stream) {
  const float* Q = (const float*)d_in[0];
  const float* K = (const float*)d_in[1];
  const float* V = (const float*)d_in[2];
  const int*   M = (const int*)d_in[3];
  float* O = (float*)d_out;
  attn_fwd<<<dim3(256), dim3(256), 0, stream>>>(Q, K, V, M, O);
}

// Round 2
// 336.598 us; speedup vs baseline: 1.1445x; 1.1445x over previous
//
#include <hip/hip_runtime.h>
#include <hip/hip_bf16.h>

// Flash-attention fwd, causal + key-padding. B=8,S=2048,D=512 fp32 in/out.
// Round 2: prologue bf16 convert (Q,K) + transpose (V^T) into ws; chunked
// split-KV 2-pass for load balance; global_load_lds staging; 2 blocks/CU.

typedef short bf16x8 __attribute__((ext_vector_type(8)));
typedef short s4v    __attribute__((ext_vector_type(4)));
typedef float f32x4  __attribute__((ext_vector_type(4)));
typedef float f4v    __attribute__((ext_vector_type(4)));
typedef float f2v    __attribute__((ext_vector_type(2)));
typedef unsigned int u32;

#define DEVINL __device__ __forceinline__

constexpr int kS = 2048;
constexpr int kD = 512;
constexpr int kB = 8;
constexpr int QT = 32;          // q-tiles per batch at M=64
constexpr int KROW = kD + 8;    // 520 shorts: pad keeps K-frag reads bank-balanced
constexpr float kC = 1.4426950408889634f * 0.044194173824159216f; // log2e/sqrt(512)
constexpr size_t kSlotB = (size_t)64 * kD * 2 + 64 * 4 * 2;       // 66048 B

DEVINL float fast_exp2(float x) {
  float r; asm("v_exp_f32 %0, %1" : "=v"(r) : "v"(x)); return r;
}
DEVINL short f2b(float f) {
  return (short)__builtin_bit_cast(unsigned short, __float2bfloat16(f));
}
DEVINL f32x4 mfma16(bf16x8 a, bf16x8 b, f32x4 c) {
  return __builtin_amdgcn_mfma_f32_16x16x32_bf16(a, b, c, 0, 0, 0);
}
DEVINL void gl_lds16(const void* g, void* l) {
  __builtin_amdgcn_global_load_lds(
      (const __attribute__((address_space(1))) u32*)g,
      (__attribute__((address_space(3))) u32*)l, 16, 0, 0);
}
DEVINL float bflo(u32 u) { return __builtin_bit_cast(float, u << 16); }
DEVINL float bfhi(u32 u) { return __builtin_bit_cast(float, u & 0xffff0000u); }

// ---------------- prologue: f32 -> bf16 convert for Q and K ----------------
__global__ __launch_bounds__(256) void conv_qk(
    const float* __restrict__ Q, const float* __restrict__ K,
    short* __restrict__ Qb, short* __restrict__ Kb) {
  const size_t n4 = (size_t)kB * kS * kD / 4;
  for (size_t i = (size_t)blockIdx.x * 256 + threadIdx.x; i < 2 * n4;
       i += (size_t)gridDim.x * 256) {
    const float* src; short* dst; size_t j;
    if (i < n4) { src = Q; dst = Qb; j = i; } else { src = K; dst = Kb; j = i - n4; }
    f4v v = *(const f4v*)(src + j * 4);
    s4v o = {f2b(v[0]), f2b(v[1]), f2b(v[2]), f2b(v[3])};
    *(s4v*)(dst + j * 4) = o;
  }
}

// ---------------- prologue: V[b][s][d] f32 -> V^T[b][d][s] bf16 ------------
__global__ __launch_bounds__(256) void transV(const float* __restrict__ V,
                                              short* __restrict__ Vt) {
  __shared__ float Tl[64][65];
  const int blk = blockIdx.x;
  const int b = blk >> 8, r = blk & 255;
  const int s0 = (r >> 3) * 64, d0 = (r & 7) * 64;
  const int t = threadIdx.x;
#pragma unroll
  for (int i = 0; i < 4; ++i) {
    int v = t + i * 256;            // vec4 id 0..1023 in 64x64 tile
    int row = v >> 4, cq = v & 15;  // 16 lanes x 16B = 256B coalesced per row
    f4v x = *(const f4v*)(V + ((size_t)(b * kS + s0 + row)) * kD + d0 + cq * 4);
    *(f4v*)&Tl[row][cq * 4] = x;
  }
  __syncthreads();
  const int dd = t >> 2, q = t & 3;
  short out[16];
#pragma unroll
  for (int j = 0; j < 16; ++j) out[j] = f2b(Tl[q * 16 + j][dd]);
  short* dp = Vt + ((size_t)(b * kD + d0 + dd)) * kS + s0 + q * 16;
  *(bf16x8*)dp = *(const bf16x8*)&out[0];
  *(bf16x8*)(dp + 8) = *(const bf16x8*)&out[8];
}

// ---------------- pass 1: chunked flash attention --------------------------
__global__ __launch_bounds__(256, 2) void attn_p1(
    const short* __restrict__ Qb, const short* __restrict__ Kb,
    const short* __restrict__ Vt, const int* __restrict__ Mp,
    float* __restrict__ Op, char* __restrict__ Part, int TC) {
  __shared__ __align__(16) short Klds[32 * KROW];   // 33,280 B
  __shared__ __align__(16) short Vlds[kD * 32];     // 32,768 B  [d][kv] 64B rows
  __shared__ __align__(16) short Plds[4 * 16 * 40]; //  5,120 B
  __shared__ unsigned char Mlds[kS];                //  2,048 B   total 73,216 B

  const int tid = threadIdx.x, lane = tid & 63, w = tid >> 6;
  const int b = blockIdx.x & 7;
  const int PB = gridDim.x >> 3;
  const int jj = PB - 1 - (blockIdx.x >> 3);  // big-first dispatch order

  // decode jj -> (qt, sub) over ascending-qt chunk enumeration
  int j = jj, qt = 0, sub = 0;
  for (qt = 0; qt < QT; ++qt) {
    int c = (2 * qt + 2 + TC - 1) / TC;
    if (j < c) { sub = j; break; }
    j -= c;
  }
  const int nc = (2 * qt + 2 + TC - 1) / TC;
  const int qbase = qt * 64;

  for (int i = tid; i < kS; i += 256) Mlds[i] = (unsigned char)Mp[(size_t)b * kS + i];

  const int l15 = lane & 15, lg = lane >> 4;

  // Q A-fragments resident (bf16 direct loads)
  bf16x8 qa[16];
  {
    const short* qp = Qb + ((size_t)(b * kS) + qbase + w * 16 + l15) * kD + lg * 8;
#pragma unroll
    for (int k = 0; k < 16; ++k) qa[k] = *(const bf16x8*)(qp + k * 32);
  }

  f32x4 acc[32];
#pragma unroll
  for (int dc = 0; dc < 32; ++dc) acc[dc] = f32x4{0.f, 0.f, 0.f, 0.f};
  float mrow[4] = {-1e30f, -1e30f, -1e30f, -1e30f};
  float lsum[4] = {0.f, 0.f, 0.f, 0.f};

  short* Pl = &Plds[w * 16 * 40];
  const int t0 = sub * TC, t1 = min(t0 + TC, 2 * qt + 2);

  for (int t = t0; t < t1; ++t) {
    const int kv0 = t * 32;
    __syncthreads();  // previous tile's LDS reads done

    // ---- stage K tile via global_load_lds (1 row = 1KB per instr) ----
    {
      const short* kb = Kb + ((size_t)(b * kS) + kv0) * kD;
#pragma unroll
      for (int r8 = 0; r8 < 8; ++r8) {
        const int row = w * 8 + r8;
        gl_lds16(kb + (size_t)row * kD + lane * 8, &Klds[row * KROW]);
      }
      // ---- stage V^T tile: 16 d-rows x 64B per instr ----
      const short* vt = Vt + (size_t)(b * kD) * kS + kv0;
#pragma unroll
      for (int r8 = 0; r8 < 8; ++r8) {
        const int i = w * 8 + r8;
        const int d = i * 16 + (lane >> 2);
        gl_lds16(vt + (size_t)d * kS + (lane & 3) * 8, &Vlds[i * 16 * 32]);
      }
    }
    __syncthreads();  // drains vmcnt (global_load_lds) + barrier

    // ---- QK^T: S[16q x 32kv], 4 independent MFMA chains ----
    f32x4 sA = {0.f,0.f,0.f,0.f}, sB = {0.f,0.f,0.f,0.f};
    f32x4 sC = {0.f,0.f,0.f,0.f}, sD = {0.f,0.f,0.f,0.f};
    const short* krow0 = &Klds[l15 * KROW + lg * 8];
    const short* krow1 = krow0 + 16 * KROW;
    __builtin_amdgcn_s_setprio(1);
#pragma unroll
    for (int k = 0; k < 16; k += 2) {
      bf16x8 b00 = *(const bf16x8*)(krow0 + k * 32);
      bf16x8 b10 = *(const bf16x8*)(krow1 + k * 32);
      bf16x8 b01 = *(const bf16x8*)(krow0 + (k + 1) * 32);
      bf16x8 b11 = *(const bf16x8*)(krow1 + (k + 1) * 32);
      sA = mfma16(qa[k], b00, sA);
      sB = mfma16(qa[k], b10, sB);
      sC = mfma16(qa[k + 1], b01, sC);
      sD = mfma16(qa[k + 1], b11, sD);
    }
    __builtin_amdgcn_s_setprio(0);
    f32x4 s0 = sA + sC;  // kv col kv0+l15,    rows lg*4+j
    f32x4 s1 = sB + sD;  // kv col kv0+16+l15

    // ---- mask + row max ----
    const int kvg0 = kv0 + l15, kvg1 = kvg0 + 16;
    const int mk0 = Mlds[kvg0], mk1 = Mlds[kvg1];
    const int qrow0 = qbase + w * 16 + lg * 4;
    float rm[4];
#pragma unroll
    for (int jx = 0; jx < 4; ++jx) {
      const int q = qrow0 + jx;
      float x0 = (kvg0 <= q && mk0 != 0) ? s0[jx] : -1e30f;
      float x1 = (kvg1 <= q && mk1 != 0) ? s1[jx] : -1e30f;
      s0[jx] = x0; s1[jx] = x1;
      rm[jx] = fmaxf(x0, x1);
    }
#pragma unroll
    for (int sh = 1; sh <= 8; sh <<= 1) {
#pragma unroll
      for (int jx = 0; jx < 4; ++jx) rm[jx] = fmaxf(rm[jx], __shfl_xor(rm[jx], sh));
    }

    // ---- defer-max rescale (T13) ----
    bool need = false;
#pragma unroll
    for (int jx = 0; jx < 4; ++jx) need |= ((rm[jx] - mrow[jx]) * kC > 8.0f);
    if (__any(need)) {
#pragma unroll
      for (int jx = 0; jx < 4; ++jx) {
        float mn = fmaxf(mrow[jx], rm[jx]);
        float corr = fast_exp2((mrow[jx] - mn) * kC);
        mrow[jx] = mn;
        lsum[jx] *= corr;
#pragma unroll
        for (int dc = 0; dc < 32; ++dc) acc[dc][jx] *= corr;
      }
    }

    // ---- P = exp2((s-m)*kC); row-sum; C->A layout via wave-local LDS ----
    float ts[4];
#pragma unroll
    for (int jx = 0; jx < 4; ++jx) {
      float p0 = fast_exp2((s0[jx] - mrow[jx]) * kC);
      float p1 = fast_exp2((s1[jx] - mrow[jx]) * kC);
      ts[jx] = p0 + p1;
      Pl[(lg * 4 + jx) * 40 + l15]      = f2b(p0);
      Pl[(lg * 4 + jx) * 40 + 16 + l15] = f2b(p1);
    }
#pragma unroll
    for (int sh = 1; sh <= 8; sh <<= 1) {
#pragma unroll
      for (int jx = 0; jx < 4; ++jx) ts[jx] += __shfl_xor(ts[jx], sh);
    }
#pragma unroll
    for (int jx = 0; jx < 4; ++jx) lsum[jx] += ts[jx];

    // ---- PV ----
    bf16x8 pf = *(const bf16x8*)&Pl[l15 * 40 + lg * 8];
    __builtin_amdgcn_s_setprio(1);
#pragma unroll
    for (int dc = 0; dc < 32; ++dc) {
      const bf16x8 vf = *(const bf16x8*)&Vlds[(dc * 16 + l15) * 32 + lg * 8];
      acc[dc] = mfma16(pf, vf, acc[dc]);
    }
    __builtin_amdgcn_s_setprio(0);
  }

  // ---- epilogue ----
  if (nc == 1) {
#pragma unroll
    for (int jx = 0; jx < 4; ++jx) {
      const float inv = __builtin_amdgcn_rcpf(lsum[jx]);
      float* op = Op + ((size_t)(b * kS) + qbase + w * 16 + lg * 4 + jx) * kD + l15;
#pragma unroll
      for (int dc = 0; dc < 32; ++dc) op[dc * 16] = acc[dc][jx] * inv;
    }
  } else {
    char* sp = Part + ((size_t)b * PB + jj) * kSlotB;
    short* po = (short*)sp;
    float* pm = (float*)(sp + 65536);
#pragma unroll
    for (int jx = 0; jx < 4; ++jx) {
      const int row = w * 16 + lg * 4 + jx;
#pragma unroll
      for (int dc = 0; dc < 32; ++dc) po[row * kD + dc * 16 + l15] = f2b(acc[dc][jx]);
      if (l15 == 0) { pm[row] = mrow[jx]; pm[64 + row] = lsum[jx]; }
    }
  }
}

// ---------------- pass 2: merge chunk partials -----------------------------
__global__ __launch_bounds__(256) void attn_p2(const char* __restrict__ Part,
                                               float* __restrict__ Op,
                                               int TC, int PB) {
  const int b = blockIdx.x & 7, idx = blockIdx.x >> 3;
  int qt = 0, pre = 0, nc = 0, seen = 0;
  for (int q = 0; q < QT; ++q) {
    int c = (2 * q + 2 + TC - 1) / TC;
    if (c > 1) {
      if (seen == idx) { qt = q; nc = c; break; }
      seen++;
    }
    pre += c;
  }
  const int t = threadIdx.x;
  const char* base = Part + ((size_t)b * PB + pre) * kSlotB;
  for (int row = 0; row < 64; ++row) {
    float M = -1e30f;
    for (int c = 0; c < nc; ++c)
      M = fmaxf(M, *(const float*)(base + c * kSlotB + 65536 + row * 4));
    float lt = 0.f;
    for (int c = 0; c < nc; ++c) {
      float mc = *(const float*)(base + c * kSlotB + 65536 + row * 4);
      float lc = *(const float*)(base + c * kSlotB + 65536 + 256 + row * 4);
      lt += lc * fast_exp2((mc - M) * kC);
    }
    const float inv = 1.0f / lt;
    float a0 = 0.f, a1 = 0.f;
    for (int c = 0; c < nc; ++c) {
      float mc = *(const float*)(base + c * kSlotB + 65536 + row * 4);
      float e = fast_exp2((mc - M) * kC);
      u32 u = *(const u32*)(base + c * kSlotB + ((size_t)row * kD + t * 2) * 2);
      a0 += e * bflo(u);
      a1 += e * bfhi(u);
    }
    f2v o = {a0 * inv, a1 * inv};
    *(f2v*)(Op + ((size_t)(b * kS) + qt * 64 + row) * kD + t * 2) = o;
  }
}

// ---------------- legacy fallback (round-1 kernel, f32 direct) -------------
__global__ __launch_bounds__(256) void attn_legacy(
    const float* __restrict__ Qp, const float* __restrict__ Kp,
    const float* __restrict__ Vp, const int* __restrict__ Mp,
    float* __restrict__ Op) {
  __shared__ __align__(16) short Klds[32 * KROW];
  __shared__ __align__(16) short Vlds[32 * kD];
  __shared__ __align__(16) short Plds[4 * 16 * 40];
  __shared__ int Mlds[kS];
  const int tid = threadIdx.x, lane = tid & 63, w = tid >> 6;
  const int bb = blockIdx.x & 7, qt = blockIdx.x >> 3, qb = qt * 64;
  for (int i = tid; i < kS; i += 256) Mlds[i] = Mp[(size_t)bb * kS + i];
  const int l15 = lane & 15, lg = lane >> 4;
  bf16x8 qa[16];
  {
    const float* qp = Qp + ((size_t)bb * kS + qb + w * 16 + l15) * kD + lg * 8;
#pragma unroll
    for (int k = 0; k < 16; ++k) {
      f4v a = *(const f4v*)(qp + k * 32);
      f4v c = *(const f4v*)(qp + k * 32 + 4);
      bf16x8 q8 = {f2b(a[0]), f2b(a[1]), f2b(a[2]), f2b(a[3]),
                   f2b(c[0]), f2b(c[1]), f2b(c[2]), f2b(c[3])};
      qa[k] = q8;
    }
  }
  f32x4 acc[32];
#pragma unroll
  for (int dc = 0; dc < 32; ++dc) acc[dc] = f32x4{0.f, 0.f, 0.f, 0.f};
  float mrow[4] = {-1e30f, -1e30f, -1e30f, -1e30f};
  float lsum[4] = {0.f, 0.f, 0.f, 0.f};
  short* Pl = &Plds[w * 16 * 40];
  const int vphys = ((lg ^ ((lane >> 2) & 3)) * 16);
  const int nt = 2 * qt + 2;
  for (int t = 0; t < nt; ++t) {
    const int kv0 = t * 32;
    __syncthreads();
    {
      const int r = tid >> 3, dg = tid & 7;
      const float* src = Kp + ((size_t)bb * kS + kv0 + r) * kD + dg * 64;
      short* dst = &Klds[r * KROW + dg * 64];
#pragma unroll
      for (int i = 0; i < 16; ++i) {
        f4v v = *(const f4v*)(src + i * 4);
        s4v s = {f2b(v[0]), f2b(v[1]), f2b(v[2]), f2b(v[3])};
        *(s4v*)(dst + i * 4) = s;
      }
    }
    {
      const int kvq = tid & 7, dqi = tid >> 3;
      const float* vbase = Vp + ((size_t)bb * kS + kv0 + kvq * 4) * kD;
#pragma unroll
      for (int it = 0; it < 4; ++it) {
        const int dq = dqi + 32 * it;
        f4v v0 = *(const f4v*)(vbase + 0 * kD + dq * 4);
        f4v v1 = *(const f4v*)(vbase + 1 * kD + dq * 4);
        f4v v2 = *(const f4v*)(vbase + 2 * kD + dq * 4);
        f4v v3 = *(const f4v*)(vbase + 3 * kD + dq * 4);
        const int pch = (((kvq >> 1) ^ (dq & 3)) * 16) + (kvq & 1) * 8;
#pragma unroll
        for (int c = 0; c < 4; ++c) {
          s4v s = {f2b(v0[c]), f2b(v1[c]), f2b(v2[c]), f2b(v3[c])};
          *(s4v*)((char*)Vlds + (dq * 4 + c) * 64 + pch) = s;
        }
      }
    }
    __syncthreads();
    f32x4 sA = {0.f,0.f,0.f,0.f}, sB = {0.f,0.f,0.f,0.f};
    f32x4 sC = {0.f,0.f,0.f,0.f}, sD = {0.f,0.f,0.f,0.f};
    const short* krow0 = &Klds[l15 * KROW + lg * 8];
    const short* krow1 = krow0 + 16 * KROW;
#pragma unroll
    for (int k = 0; k < 16; k += 2) {
      bf16x8 b00 = *(const bf16x8*)(krow0 + k * 32);
      bf16x8 b10 = *(const bf16x8*)(krow1 + k * 32);
      bf16x8 b01 = *(const bf16x8*)(krow0 + (k + 1) * 32);
      bf16x8 b11 = *(const bf16x8*)(krow1 + (k + 1) * 32);
      sA = mfma16(qa[k], b00, sA);
      sB = mfma16(qa[k], b10, sB);
      sC = mfma16(qa[k + 1], b01, sC);
      sD = mfma16(qa[k + 1], b11, sD);
    }
    f32x4 s0 = sA + sC, s1 = sB + sD;
    const int kvg0 = kv0 + l15, kvg1 = kvg0 + 16;
    const int mk0 = Mlds[kvg0], mk1 = Mlds[kvg1];
    const int qrow0 = qb + w * 16 + lg * 4;
    float rm[4];
#pragma unroll
    for (int jx = 0; jx < 4; ++jx) {
      const int q = qrow0 + jx;
      float x0 = (kvg0 <= q && mk0 != 0) ? s0[jx] : -1e30f;
      float x1 = (kvg1 <= q && mk1 != 0) ? s1[jx] : -1e30f;
      s0[jx] = x0; s1[jx] = x1;
      rm[jx] = fmaxf(x0, x1);
    }
#pragma unroll
    for (int sh = 1; sh <= 8; sh <<= 1) {
#pragma unroll
      for (int jx = 0; jx < 4; ++jx) rm[jx] = fmaxf(rm[jx], __shfl_xor(rm[jx], sh));
    }
    bool need = false;
#pragma unroll
    for (int jx = 0; jx < 4; ++jx) need |= ((rm[jx] - mrow[jx]) * kC > 8.0f);
    if (__any(need)) {
#pragma unroll
      for (int jx = 0; jx < 4; ++jx) {
        float mn = fmaxf(mrow[jx], rm[jx]);
        float corr = fast_exp2((mrow[jx] - mn) * kC);
        mrow[jx] = mn;
        lsum[jx] *= corr;
#pragma unroll
        for (int dc = 0; dc < 32; ++dc) acc[dc][jx] *= corr;
      }
    }
    float ts[4];
#pragma unroll
    for (int jx = 0; jx < 4; ++jx) {
      float p0 = fast_exp2((s0[jx] - mrow[jx]) * kC);
      float p1 = fast_exp2((s1[jx] - mrow[jx]) * kC);
      ts[jx] = p0 + p1;
      Pl[(lg * 4 + jx) * 40 + l15]      = f2b(p0);
      Pl[(lg * 4 + jx) * 40 + 16 + l15] = f2b(p1);
    }
#pragma unroll
    for (int sh = 1; sh <= 8; sh <<= 1) {
#pragma unroll
      for (int jx = 0; jx < 4; ++jx) ts[jx] += __shfl_xor(ts[jx], sh);
    }
#pragma unroll
    for (int jx = 0; jx < 4; ++jx) lsum[jx] += ts[jx];
    bf16x8 pf = *(const bf16x8*)&Pl[l15 * 40 + lg * 8];
#pragma unroll
    for (int dc = 0; dc < 32; ++dc) {
      const bf16x8 vf = *(const bf16x8*)((const char*)Vlds + (dc * 16 + l15) * 64 + vphys);
      acc[dc] = mfma16(pf, vf, acc[dc]);
    }
  }
#pragma unroll
  for (int jx = 0; jx < 4; ++jx) {
    const float inv = __builtin_amdgcn_rcpf(lsum[jx]);
    float* op = Op + ((size_t)bb * kS + qb + w * 16 + lg * 4 + jx) * kD + l15;
#pragma unroll
    for (int dc = 0; dc < 32; ++dc) op[dc * 16] = acc[dc][jx] * inv;
  }
}

extern "C" void kernel_launch(void* const* d_in, const int* in_sizes, int n_in,
                              void* d_out, int out_size, void* d_ws, size_t ws_size,
                              hipStream_t stream) {
  const float* Q = (const float*)d_in[0];
  const float* K = (const float*)d_in[1];
  const float* V = (const float*)d_in[2];
  const int*   M = (const int*)d_in[3];
  float* O = (float*)d_out;

  const size_t tensb = (size_t)kB * kS * kD * 2;  // 16 MiB bf16 tensor
  const size_t conv = 3 * tensb;                  // Qb + Kb + Vt

  if (ws_size < conv) {  // no room for prologue: proven round-1 path
    attn_legacy<<<dim3(256), dim3(256), 0, stream>>>(Q, K, V, M, O);
    return;
  }

  short* Qb = (short*)d_ws;
  short* Kb = Qb + (size_t)kB * kS * kD;
  short* Vt = Kb + (size_t)kB * kS * kD;
  char* Part = (char*)d_ws + conv;

  int TC = 64;  // single chunk per q-tile (no ws partials needed)
  {
    int pb16 = 0;
    for (int q = 0; q < QT; ++q) pb16 += (2 * q + 2 + 15) / 16;
    if (ws_size >= conv + (size_t)kB * pb16 * kSlotB) TC = 16;
  }

  conv_qk<<<dim3(2048), dim3(256), 0, stream>>>(Q, K, Qb, Kb);
  transV<<<dim3(2048), dim3(256), 0, stream>>>(V, Vt);

  int PB = 0, nq2 = 0;
  for (int q = 0; q < QT; ++q) {
    int c = (2 * q + 2 + TC - 1) / TC;
    PB += c;
    if (c > 1) nq2++;
  }
  attn_p1<<<dim3(kB * PB), dim3(256), 0, stream>>>(Qb, Kb, Vt, M, O, Part, TC);
  if (nq2 > 0)
    attn_p2<<<dim3(kB * nq2), dim3(256), 0, stream>>>(Part, O, TC, PB);
}

// Round 3
// 310.448 us; speedup vs baseline: 1.2410x; 1.0842x over previous
//
#include <hip/hip_runtime.h>
#include <hip/hip_bf16.h>

// Flash-attention fwd, causal + key-padding. B=8,S=2048,D=512 fp32 in/out.
// Round 3: bank-conflict-free XOR-swizzled K and V LDS layouts (both-sides
// swizzle with global_load_lds), slim fused prologue (K->bf16, V->V^T bf16),
// chunked split-KV 2-pass, 2 blocks/CU.

typedef short bf16x8 __attribute__((ext_vector_type(8)));
typedef short s4v    __attribute__((ext_vector_type(4)));
typedef float f32x4  __attribute__((ext_vector_type(4)));
typedef float f4v    __attribute__((ext_vector_type(4)));
typedef float f2v    __attribute__((ext_vector_type(2)));
typedef unsigned int u32;

#define DEVINL __device__ __forceinline__

constexpr int kS = 2048;
constexpr int kD = 512;
constexpr int kB = 8;
constexpr int QT = 32;          // q-tiles per batch at M=64
constexpr int KROW = kD + 8;    // legacy-path K row stride
constexpr float kC = 1.4426950408889634f * 0.044194173824159216f; // log2e/sqrt(512)
constexpr size_t kSlotB = (size_t)64 * kD * 2 + 64 * 4 * 2;       // 66048 B

DEVINL float fast_exp2(float x) {
  float r; asm("v_exp_f32 %0, %1" : "=v"(r) : "v"(x)); return r;
}
DEVINL short f2b(float f) {
  return (short)__builtin_bit_cast(unsigned short, __float2bfloat16(f));
}
DEVINL f32x4 mfma16(bf16x8 a, bf16x8 b, f32x4 c) {
  return __builtin_amdgcn_mfma_f32_16x16x32_bf16(a, b, c, 0, 0, 0);
}
DEVINL void gl_lds16(const void* g, void* l) {
  __builtin_amdgcn_global_load_lds(
      (const __attribute__((address_space(1))) u32*)g,
      (__attribute__((address_space(3))) u32*)l, 16, 0, 0);
}
DEVINL float bflo(u32 u) { return __builtin_bit_cast(float, u << 16); }
DEVINL float bfhi(u32 u) { return __builtin_bit_cast(float, u & 0xffff0000u); }

// ------------- fused prologue: K f32->bf16 ; V -> V^T[b][d][s] bf16 --------
__global__ __launch_bounds__(256) void prep(
    const float* __restrict__ K, const float* __restrict__ V,
    short* __restrict__ Kb, short* __restrict__ Vt) {
  __shared__ float Tl[64][65];
  const int blk = blockIdx.x;
  if (blk < 1024) {  // ---- K convert, coalesced grid-stride ----
    const size_t n4 = (size_t)kB * kS * kD / 4;
    for (size_t i = (size_t)blk * 256 + threadIdx.x; i < n4;
         i += (size_t)1024 * 256) {
      f4v v = *(const f4v*)(K + i * 4);
      s4v o = {f2b(v[0]), f2b(v[1]), f2b(v[2]), f2b(v[3])};
      *(s4v*)(Kb + i * 4) = o;
    }
  } else {           // ---- V transpose via 64x64 LDS tile ----
    const int r = blk - 1024;           // 0..2047
    const int b = r >> 8, rr = r & 255;
    const int s0 = (rr >> 3) * 64, d0 = (rr & 7) * 64;
    const int t = threadIdx.x;
#pragma unroll
    for (int i = 0; i < 4; ++i) {
      int v = t + i * 256;
      int row = v >> 4, cq = v & 15;
      f4v x = *(const f4v*)(V + ((size_t)(b * kS + s0 + row)) * kD + d0 + cq * 4);
      *(f4v*)&Tl[row][cq * 4] = x;
    }
    __syncthreads();
    const int dd = t >> 2, q = t & 3;
    short out[16];
#pragma unroll
    for (int j = 0; j < 16; ++j) out[j] = f2b(Tl[q * 16 + j][dd]);
    short* dp = Vt + ((size_t)(b * kD + d0 + dd)) * kS + s0 + q * 16;
    *(bf16x8*)dp = *(const bf16x8*)&out[0];
    *(bf16x8*)(dp + 8) = *(const bf16x8*)&out[8];
  }
}

// ---------------- pass 1: chunked flash attention --------------------------
// K LDS: row-major [32][512] bf16, 16B-chunk swizzle: phys = logical ^ (row&7)
// V LDS: superrow sr=d>>2, 256B each; chunk phys = ((d&3)*4+lg) ^ (sr&7)
__global__ __launch_bounds__(256, 2) void attn_p1(
    const float* __restrict__ Qp, const short* __restrict__ Kb,
    const short* __restrict__ Vt, const int* __restrict__ Mp,
    float* __restrict__ Op, char* __restrict__ Part, int TC) {
  __shared__ __align__(16) short Klds[32 * 512];    // 32,768 B
  __shared__ __align__(16) short Vlds[128 * 128];   // 32,768 B
  __shared__ __align__(16) short Plds[4 * 16 * 40]; //  5,120 B
  __shared__ unsigned char Mlds[kS];                //  2,048 B  total 72,704

  const int tid = threadIdx.x, lane = tid & 63, w = tid >> 6;
  const int b = blockIdx.x & 7;
  const int PB = gridDim.x >> 3;
  const int jj = PB - 1 - (blockIdx.x >> 3);  // big-first dispatch order

  int j = jj, qt = 0, sub = 0;
  for (qt = 0; qt < QT; ++qt) {
    int c = (2 * qt + 2 + TC - 1) / TC;
    if (j < c) { sub = j; break; }
    j -= c;
  }
  const int nc = (2 * qt + 2 + TC - 1) / TC;
  const int qbase = qt * 64;

  for (int i = tid; i < kS; i += 256) Mlds[i] = (unsigned char)Mp[(size_t)b * kS + i];

  const int l15 = lane & 15, lg = lane >> 4;

  // Q A-fragments resident (f32 load + convert, once per block)
  bf16x8 qa[16];
  {
    const float* qp = Qp + ((size_t)(b * kS) + qbase + w * 16 + l15) * kD + lg * 8;
#pragma unroll
    for (int k = 0; k < 16; ++k) {
      f4v a = *(const f4v*)(qp + k * 32);
      f4v c = *(const f4v*)(qp + k * 32 + 4);
      bf16x8 q8 = {f2b(a[0]), f2b(a[1]), f2b(a[2]), f2b(a[3]),
                   f2b(c[0]), f2b(c[1]), f2b(c[2]), f2b(c[3])};
      qa[k] = q8;
    }
  }

  f32x4 acc[32];
#pragma unroll
  for (int dc = 0; dc < 32; ++dc) acc[dc] = f32x4{0.f, 0.f, 0.f, 0.f};
  float mrow[4] = {-1e30f, -1e30f, -1e30f, -1e30f};
  float lsum[4] = {0.f, 0.f, 0.f, 0.f};

  short* Pl = &Plds[w * 16 * 40];

  // ---- precomputed swizzled read base pointers ----
  // K (QK^T B-frag): byte(row=l15, logical chunk c=4k+lg) = row*1024 + (c^(row&7))*16
  //   = base2 + 32sh*(k ^ kx4), base2 = row*512 + (lg^(l15&3))*8, kx4=(l15>>2)&1
  const int kx4 = (l15 >> 2) & 1;
  const short* kbase2 = &Klds[l15 * 512 + ((lg ^ (l15 & 3)) << 3)];
  const short* kpE = kbase2 + (kx4 << 5);  // even logical k
  const short* kpO = kbase2 - (kx4 << 5);  // odd logical k
  // V (PV B-frag): shorts(dc) = dc*512 + vbase(parity of dc)
  const int vcom = (l15 >> 2) * 128 + ((l15 >> 1) & 1) * 64 + ((lg ^ (l15 >> 2)) << 3);
  const short* vE = &Vlds[vcom + (l15 & 1) * 32];
  const short* vO = &Vlds[vcom + ((l15 & 1) ^ 1) * 32];

  const int t0 = sub * TC, t1 = min(t0 + TC, 2 * qt + 2);

  for (int t = t0; t < t1; ++t) {
    const int kv0 = t * 32;
    __syncthreads();  // previous tile's LDS reads done

    // ---- stage K tile (inverse-swizzled global src, linear LDS dest) ----
    {
      const short* kb = Kb + ((size_t)(b * kS) + kv0) * kD;
      const short* vt = Vt + (size_t)(b * kD) * kS + kv0;
      const int li = lane & 15, lh = lane >> 4;
#pragma unroll
      for (int r8 = 0; r8 < 8; ++r8) {
        const int row = w * 8 + r8;           // row&7 == r8&7, but w*8 keeps r8<8
        gl_lds16(kb + (size_t)row * kD + ((lane ^ (row & 7)) << 3),
                 &Klds[row * 512]);
      }
#pragma unroll
      for (int r8 = 0; r8 < 8; ++r8) {
        const int i = w * 8 + r8;             // 1KB chunk id, superrows 4i..4i+3
        const int sr = 4 * i + lh;
        const int logical = li ^ (4 * (i & 1) + lh);
        const int d = sr * 4 + (logical >> 2);
        gl_lds16(vt + (size_t)d * kS + ((logical & 3) << 3), &Vlds[i * 512]);
      }
    }
    __syncthreads();  // drains vmcnt + barrier

    // ---- QK^T: S[16q x 32kv] ----
    f32x4 sA = {0.f,0.f,0.f,0.f}, sB = {0.f,0.f,0.f,0.f};
    f32x4 sC = {0.f,0.f,0.f,0.f}, sD = {0.f,0.f,0.f,0.f};
    __builtin_amdgcn_s_setprio(1);
#pragma unroll
    for (int k = 0; k < 16; k += 2) {
      const short* pa = kpE + (k << 5);
      const short* pb = kpO + ((k + 1) << 5);
      bf16x8 b00 = *(const bf16x8*)(pa);
      bf16x8 b10 = *(const bf16x8*)(pa + 16 * 512);
      bf16x8 b01 = *(const bf16x8*)(pb);
      bf16x8 b11 = *(const bf16x8*)(pb + 16 * 512);
      sA = mfma16(qa[k], b00, sA);
      sB = mfma16(qa[k], b10, sB);
      sC = mfma16(qa[k + 1], b01, sC);
      sD = mfma16(qa[k + 1], b11, sD);
    }
    __builtin_amdgcn_s_setprio(0);
    f32x4 s0 = sA + sC;  // kv col kv0+l15,    rows lg*4+j
    f32x4 s1 = sB + sD;  // kv col kv0+16+l15

    // ---- mask + row max ----
    const int kvg0 = kv0 + l15, kvg1 = kvg0 + 16;
    const int mk0 = Mlds[kvg0], mk1 = Mlds[kvg1];
    const int qrow0 = qbase + w * 16 + lg * 4;
    float rm[4];
#pragma unroll
    for (int jx = 0; jx < 4; ++jx) {
      const int q = qrow0 + jx;
      float x0 = (kvg0 <= q && mk0 != 0) ? s0[jx] : -1e30f;
      float x1 = (kvg1 <= q && mk1 != 0) ? s1[jx] : -1e30f;
      s0[jx] = x0; s1[jx] = x1;
      rm[jx] = fmaxf(x0, x1);
    }
#pragma unroll
    for (int sh = 1; sh <= 8; sh <<= 1) {
#pragma unroll
      for (int jx = 0; jx < 4; ++jx) rm[jx] = fmaxf(rm[jx], __shfl_xor(rm[jx], sh));
    }

    // ---- defer-max rescale (T13) ----
    bool need = false;
#pragma unroll
    for (int jx = 0; jx < 4; ++jx) need |= ((rm[jx] - mrow[jx]) * kC > 8.0f);
    if (__any(need)) {
#pragma unroll
      for (int jx = 0; jx < 4; ++jx) {
        float mn = fmaxf(mrow[jx], rm[jx]);
        float corr = fast_exp2((mrow[jx] - mn) * kC);
        mrow[jx] = mn;
        lsum[jx] *= corr;
#pragma unroll
        for (int dc = 0; dc < 32; ++dc) acc[dc][jx] *= corr;
      }
    }

    // ---- P = exp2((s-m)*kC); row-sum; C->A layout via wave-local LDS ----
    float ts[4];
#pragma unroll
    for (int jx = 0; jx < 4; ++jx) {
      float p0 = fast_exp2((s0[jx] - mrow[jx]) * kC);
      float p1 = fast_exp2((s1[jx] - mrow[jx]) * kC);
      ts[jx] = p0 + p1;
      Pl[(lg * 4 + jx) * 40 + l15]      = f2b(p0);
      Pl[(lg * 4 + jx) * 40 + 16 + l15] = f2b(p1);
    }
#pragma unroll
    for (int sh = 1; sh <= 8; sh <<= 1) {
#pragma unroll
      for (int jx = 0; jx < 4; ++jx) ts[jx] += __shfl_xor(ts[jx], sh);
    }
#pragma unroll
    for (int jx = 0; jx < 4; ++jx) lsum[jx] += ts[jx];

    // ---- PV (swizzled V reads: 2 bases + immediate offsets) ----
    bf16x8 pf = *(const bf16x8*)&Pl[l15 * 40 + lg * 8];
    __builtin_amdgcn_s_setprio(1);
#pragma unroll
    for (int dc = 0; dc < 32; dc += 2) {
      bf16x8 vf0 = *(const bf16x8*)(vE + dc * 512);
      bf16x8 vf1 = *(const bf16x8*)(vO + (dc + 1) * 512);
      acc[dc]     = mfma16(pf, vf0, acc[dc]);
      acc[dc + 1] = mfma16(pf, vf1, acc[dc + 1]);
    }
    __builtin_amdgcn_s_setprio(0);
  }

  // ---- epilogue ----
  if (nc == 1) {
#pragma unroll
    for (int jx = 0; jx < 4; ++jx) {
      const float inv = __builtin_amdgcn_rcpf(lsum[jx]);
      float* op = Op + ((size_t)(b * kS) + qbase + w * 16 + lg * 4 + jx) * kD + l15;
#pragma unroll
      for (int dc = 0; dc < 32; ++dc) op[dc * 16] = acc[dc][jx] * inv;
    }
  } else {
    char* sp = Part + ((size_t)b * PB + jj) * kSlotB;
    short* po = (short*)sp;
    float* pm = (float*)(sp + 65536);
#pragma unroll
    for (int jx = 0; jx < 4; ++jx) {
      const int row = w * 16 + lg * 4 + jx;
#pragma unroll
      for (int dc = 0; dc < 32; ++dc) po[row * kD + dc * 16 + l15] = f2b(acc[dc][jx]);
      if (l15 == 0) { pm[row] = mrow[jx]; pm[64 + row] = lsum[jx]; }
    }
  }
}

// ---------------- pass 2: merge chunk partials -----------------------------
__global__ __launch_bounds__(256) void attn_p2(const char* __restrict__ Part,
                                               float* __restrict__ Op,
                                               int TC, int PB) {
  const int b = blockIdx.x & 7, idx = blockIdx.x >> 3;
  int qt = 0, pre = 0, nc = 0, seen = 0;
  for (int q = 0; q < QT; ++q) {
    int c = (2 * q + 2 + TC - 1) / TC;
    if (c > 1) {
      if (seen == idx) { qt = q; nc = c; break; }
      seen++;
    }
    pre += c;
  }
  const int t = threadIdx.x;
  const char* base = Part + ((size_t)b * PB + pre) * kSlotB;
  for (int row = 0; row < 64; ++row) {
    float M = -1e30f;
    for (int c = 0; c < nc; ++c)
      M = fmaxf(M, *(const float*)(base + c * kSlotB + 65536 + row * 4));
    float lt = 0.f;
    for (int c = 0; c < nc; ++c) {
      float mc = *(const float*)(base + c * kSlotB + 65536 + row * 4);
      float lc = *(const float*)(base + c * kSlotB + 65536 + 256 + row * 4);
      lt += lc * fast_exp2((mc - M) * kC);
    }
    const float inv = 1.0f / lt;
    float a0 = 0.f, a1 = 0.f;
    for (int c = 0; c < nc; ++c) {
      float mc = *(const float*)(base + c * kSlotB + 65536 + row * 4);
      float e = fast_exp2((mc - M) * kC);
      u32 u = *(const u32*)(base + c * kSlotB + ((size_t)row * kD + t * 2) * 2);
      a0 += e * bflo(u);
      a1 += e * bfhi(u);
    }
    f2v o = {a0 * inv, a1 * inv};
    *(f2v*)(Op + ((size_t)(b * kS) + qt * 64 + row) * kD + t * 2) = o;
  }
}

// ---------------- legacy fallback (round-1 kernel, f32 direct) -------------
__global__ __launch_bounds__(256) void attn_legacy(
    const float* __restrict__ Qp, const float* __restrict__ Kp,
    const float* __restrict__ Vp, const int* __restrict__ Mp,
    float* __restrict__ Op) {
  __shared__ __align__(16) short Klds[32 * KROW];
  __shared__ __align__(16) short Vlds[32 * kD];
  __shared__ __align__(16) short Plds[4 * 16 * 40];
  __shared__ int Mlds[kS];
  const int tid = threadIdx.x, lane = tid & 63, w = tid >> 6;
  const int bb = blockIdx.x & 7, qt = blockIdx.x >> 3, qb = qt * 64;
  for (int i = tid; i < kS; i += 256) Mlds[i] = Mp[(size_t)bb * kS + i];
  const int l15 = lane & 15, lg = lane >> 4;
  bf16x8 qa[16];
  {
    const float* qp = Qp + ((size_t)bb * kS + qb + w * 16 + l15) * kD + lg * 8;
#pragma unroll
    for (int k = 0; k < 16; ++k) {
      f4v a = *(const f4v*)(qp + k * 32);
      f4v c = *(const f4v*)(qp + k * 32 + 4);
      bf16x8 q8 = {f2b(a[0]), f2b(a[1]), f2b(a[2]), f2b(a[3]),
                   f2b(c[0]), f2b(c[1]), f2b(c[2]), f2b(c[3])};
      qa[k] = q8;
    }
  }
  f32x4 acc[32];
#pragma unroll
  for (int dc = 0; dc < 32; ++dc) acc[dc] = f32x4{0.f, 0.f, 0.f, 0.f};
  float mrow[4] = {-1e30f, -1e30f, -1e30f, -1e30f};
  float lsum[4] = {0.f, 0.f, 0.f, 0.f};
  short* Pl = &Plds[w * 16 * 40];
  const int vphys = ((lg ^ ((lane >> 2) & 3)) * 16);
  const int nt = 2 * qt + 2;
  for (int t = 0; t < nt; ++t) {
    const int kv0 = t * 32;
    __syncthreads();
    {
      const int r = tid >> 3, dg = tid & 7;
      const float* src = Kp + ((size_t)bb * kS + kv0 + r) * kD + dg * 64;
      short* dst = &Klds[r * KROW + dg * 64];
#pragma unroll
      for (int i = 0; i < 16; ++i) {
        f4v v = *(const f4v*)(src + i * 4);
        s4v s = {f2b(v[0]), f2b(v[1]), f2b(v[2]), f2b(v[3])};
        *(s4v*)(dst + i * 4) = s;
      }
    }
    {
      const int kvq = tid & 7, dqi = tid >> 3;
      const float* vbase = Vp + ((size_t)bb * kS + kv0 + kvq * 4) * kD;
#pragma unroll
      for (int it = 0; it < 4; ++it) {
        const int dq = dqi + 32 * it;
        f4v v0 = *(const f4v*)(vbase + 0 * kD + dq * 4);
        f4v v1 = *(const f4v*)(vbase + 1 * kD + dq * 4);
        f4v v2 = *(const f4v*)(vbase + 2 * kD + dq * 4);
        f4v v3 = *(const f4v*)(vbase + 3 * kD + dq * 4);
        const int pch = (((kvq >> 1) ^ (dq & 3)) * 16) + (kvq & 1) * 8;
#pragma unroll
        for (int c = 0; c < 4; ++c) {
          s4v s = {f2b(v0[c]), f2b(v1[c]), f2b(v2[c]), f2b(v3[c])};
          *(s4v*)((char*)Vlds + (dq * 4 + c) * 64 + pch) = s;
        }
      }
    }
    __syncthreads();
    f32x4 sA = {0.f,0.f,0.f,0.f}, sB = {0.f,0.f,0.f,0.f};
    f32x4 sC = {0.f,0.f,0.f,0.f}, sD = {0.f,0.f,0.f,0.f};
    const short* krow0 = &Klds[l15 * KROW + lg * 8];
    const short* krow1 = krow0 + 16 * KROW;
#pragma unroll
    for (int k = 0; k < 16; k += 2) {
      bf16x8 b00 = *(const bf16x8*)(krow0 + k * 32);
      bf16x8 b10 = *(const bf16x8*)(krow1 + k * 32);
      bf16x8 b01 = *(const bf16x8*)(krow0 + (k + 1) * 32);
      bf16x8 b11 = *(const bf16x8*)(krow1 + (k + 1) * 32);
      sA = mfma16(qa[k], b00, sA);
      sB = mfma16(qa[k], b10, sB);
      sC = mfma16(qa[k + 1], b01, sC);
      sD = mfma16(qa[k + 1], b11, sD);
    }
    f32x4 s0 = sA + sC, s1 = sB + sD;
    const int kvg0 = kv0 + l15, kvg1 = kvg0 + 16;
    const int mk0 = Mlds[kvg0], mk1 = Mlds[kvg1];
    const int qrow0 = qb + w * 16 + lg * 4;
    float rm[4];
#pragma unroll
    for (int jx = 0; jx < 4; ++jx) {
      const int q = qrow0 + jx;
      float x0 = (kvg0 <= q && mk0 != 0) ? s0[jx] : -1e30f;
      float x1 = (kvg1 <= q && mk1 != 0) ? s1[jx] : -1e30f;
      s0[jx] = x0; s1[jx] = x1;
      rm[jx] = fmaxf(x0, x1);
    }
#pragma unroll
    for (int sh = 1; sh <= 8; sh <<= 1) {
#pragma unroll
      for (int jx = 0; jx < 4; ++jx) rm[jx] = fmaxf(rm[jx], __shfl_xor(rm[jx], sh));
    }
    bool need = false;
#pragma unroll
    for (int jx = 0; jx < 4; ++jx) need |= ((rm[jx] - mrow[jx]) * kC > 8.0f);
    if (__any(need)) {
#pragma unroll
      for (int jx = 0; jx < 4; ++jx) {
        float mn = fmaxf(mrow[jx], rm[jx]);
        float corr = fast_exp2((mrow[jx] - mn) * kC);
        mrow[jx] = mn;
        lsum[jx] *= corr;
#pragma unroll
        for (int dc = 0; dc < 32; ++dc) acc[dc][jx] *= corr;
      }
    }
    float ts[4];
#pragma unroll
    for (int jx = 0; jx < 4; ++jx) {
      float p0 = fast_exp2((s0[jx] - mrow[jx]) * kC);
      float p1 = fast_exp2((s1[jx] - mrow[jx]) * kC);
      ts[jx] = p0 + p1;
      Pl[(lg * 4 + jx) * 40 + l15]      = f2b(p0);
      Pl[(lg * 4 + jx) * 40 + 16 + l15] = f2b(p1);
    }
#pragma unroll
    for (int sh = 1; sh <= 8; sh <<= 1) {
#pragma unroll
      for (int jx = 0; jx < 4; ++jx) ts[jx] += __shfl_xor(ts[jx], sh);
    }
#pragma unroll
    for (int jx = 0; jx < 4; ++jx) lsum[jx] += ts[jx];
    bf16x8 pf = *(const bf16x8*)&Pl[l15 * 40 + lg * 8];
#pragma unroll
    for (int dc = 0; dc < 32; ++dc) {
      const bf16x8 vf = *(const bf16x8*)((const char*)Vlds + (dc * 16 + l15) * 64 + vphys);
      acc[dc] = mfma16(pf, vf, acc[dc]);
    }
  }
#pragma unroll
  for (int jx = 0; jx < 4; ++jx) {
    const float inv = __builtin_amdgcn_rcpf(lsum[jx]);
    float* op = Op + ((size_t)bb * kS + qb + w * 16 + lg * 4 + jx) * kD + l15;
#pragma unroll
    for (int dc = 0; dc < 32; ++dc) op[dc * 16] = acc[dc][jx] * inv;
  }
}

extern "C" void kernel_launch(void* const* d_in, const int* in_sizes, int n_in,
                              void* d_out, int out_size, void* d_ws, size_t ws_size,
                              hipStream_t stream) {
  const float* Q = (const float*)d_in[0];
  const float* K = (const float*)d_in[1];
  const float* V = (const float*)d_in[2];
  const int*   M = (const int*)d_in[3];
  float* O = (float*)d_out;

  const size_t tens = (size_t)kB * kS * kD;   // elements per tensor
  const size_t convB = 2 * tens * 2;          // Kb + Vt bytes (32 MiB)

  if (ws_size < convB) {  // no room: proven round-1 path
    attn_legacy<<<dim3(256), dim3(256), 0, stream>>>(Q, K, V, M, O);
    return;
  }

  short* Kb = (short*)d_ws;
  short* Vt = Kb + tens;
  char* Part = (char*)d_ws + convB;

  int TC = 64;  // single chunk per q-tile (no partials needed)
  {
    int pb16 = 0;
    for (int q = 0; q < QT; ++q) pb16 += (2 * q + 2 + 15) / 16;
    if (ws_size >= convB + (size_t)kB * pb16 * kSlotB) TC = 16;
  }

  prep<<<dim3(3072), dim3(256), 0, stream>>>(K, V, Kb, Vt);

  int PB = 0, nq2 = 0;
  for (int q = 0; q < QT; ++q) {
    int c = (2 * q + 2 + TC - 1) / TC;
    PB += c;
    if (c > 1) nq2++;
  }
  attn_p1<<<dim3(kB * PB), dim3(256), 0, stream>>>(Q, Kb, Vt, M, O, Part, TC);
  if (nq2 > 0)
    attn_p2<<<dim3(kB * nq2), dim3(256), 0, stream>>>(Part, O, TC, PB);
}